// Round 1
// baseline (1439.715 us; speedup 1.0000x reference)
//
#include <hip/hip_runtime.h>
#include <hip/hip_bf16.h>
#include <math.h>

// Problem constants
#define BB 4
#define CC 256        // DIM
#define LL 4096       // H*W
#define DI 512        // D_INNER
#define NS 16         // D_STATE
#define RK 16         // DT_RANK

// Workspace layout (bytes). Total ~147 MB.
#define HN_OFF   0ull            // hn [16384,256] f32 ; later aliased as mout
#define XZ_OFF   16777216ull     // xz [16384,1024] ; cols 0..511 = u, later y ; cols 512..1023 = z
#define UC_OFF   83886080ull     // uc [16384,512]
#define DBL_OFF  117440512ull    // dbl [16384,48]  (dt | B | C)
#define DEL_OFF  120586240ull    // delta [16384,512]
#define S_OFF    154140672ull    // s [4,256]
#define G_OFF    154144768ull    // g [4,256]

__device__ __forceinline__ float block_sum_256(float v, float* sbuf) {
#pragma unroll
    for (int off = 32; off > 0; off >>= 1) v += __shfl_down(v, off, 64);
    int wid = threadIdx.x >> 6, lane = threadIdx.x & 63;
    __syncthreads();
    if (lane == 0) sbuf[wid] = v;
    __syncthreads();
    return sbuf[0] + sbuf[1] + sbuf[2] + sbuf[3];
}

// K1: transpose read + double LayerNorm. One block per token (256 threads = channels).
__global__ __launch_bounds__(256) void ln2_kernel(
    const float* __restrict__ x, const float* __restrict__ w1,
    const float* __restrict__ w2, const float* __restrict__ b2,
    float* __restrict__ hn)
{
    __shared__ float sbuf[4];
    int tok = blockIdx.x;            // b*4096 + l
    int b = tok >> 12;
    int l = tok & 4095;
    int c = threadIdx.x;
    float v = x[((size_t)b * CC + c) * LL + l];
    float mu = block_sum_256(v, sbuf) * (1.f / 256.f);
    float xc = v - mu;
    float var = block_sum_256(xc * xc, sbuf) * (1.f / 256.f);
    float y1 = xc * rsqrtf(var + 1e-5f) * w1[c];
    float mu2 = block_sum_256(y1, sbuf) * (1.f / 256.f);
    float y1c = y1 - mu2;
    float var2 = block_sum_256(y1c * y1c, sbuf) * (1.f / 256.f);
    float y2 = y1c * rsqrtf(var2 + 1e-5f) * w2[c] + b2[c];
    hn[(size_t)tok * CC + c] = y2;
}

// Generic fp32 GEMM: out[m,n] = sum_k A[m*lda+k] * Bw[n*ldb+k]   (both K-contiguous)
// EPI==1: out = softplus(acc + bias[n])
template<int EPI>
__global__ __launch_bounds__(256) void gemm_tn(
    const float* __restrict__ A, int lda,
    const float* __restrict__ Bw, int ldb,
    float* __restrict__ Co, int ldo,
    int N, int K, const float* __restrict__ bias)
{
    __shared__ float As[16][68];
    __shared__ float Bs[16][68];
    const int m0 = blockIdx.x * 64;
    const int n0 = blockIdx.y * 64;
    const int tid = threadIdx.x;
    const int row = tid >> 2;          // 0..63
    const int kj  = (tid & 3) << 2;    // 0,4,8,12
    const int tx = tid & 15, ty = tid >> 4;
    float acc[4][4] = {};
    for (int k0 = 0; k0 < K; k0 += 16) {
        float4 av = *reinterpret_cast<const float4*>(A + (size_t)(m0 + row) * lda + k0 + kj);
        As[kj + 0][row] = av.x; As[kj + 1][row] = av.y;
        As[kj + 2][row] = av.z; As[kj + 3][row] = av.w;
        float4 bv = make_float4(0.f, 0.f, 0.f, 0.f);
        if (n0 + row < N)
            bv = *reinterpret_cast<const float4*>(Bw + (size_t)(n0 + row) * ldb + k0 + kj);
        Bs[kj + 0][row] = bv.x; Bs[kj + 1][row] = bv.y;
        Bs[kj + 2][row] = bv.z; Bs[kj + 3][row] = bv.w;
        __syncthreads();
#pragma unroll
        for (int kk = 0; kk < 16; ++kk) {
            float a[4], b[4];
#pragma unroll
            for (int i = 0; i < 4; ++i) a[i] = As[kk][ty * 4 + i];
#pragma unroll
            for (int j = 0; j < 4; ++j) b[j] = Bs[kk][tx * 4 + j];
#pragma unroll
            for (int i = 0; i < 4; ++i)
#pragma unroll
                for (int j = 0; j < 4; ++j)
                    acc[i][j] = fmaf(a[i], b[j], acc[i][j]);
        }
        __syncthreads();
    }
#pragma unroll
    for (int i = 0; i < 4; ++i) {
        int m = m0 + ty * 4 + i;
#pragma unroll
        for (int j = 0; j < 4; ++j) {
            int n = n0 + tx * 4 + j;
            if (n < N) {
                float v = acc[i][j];
                if (EPI == 1) {
                    v += bias[n];
                    v = (v > 20.f) ? v : log1pf(__expf(v));
                }
                Co[(size_t)m * ldo + n] = v;
            }
        }
    }
}

// K3: depthwise causal conv (k=4) + bias + SiLU. u read from xz cols 0..511.
__global__ __launch_bounds__(256) void conv_silu(
    const float* __restrict__ xz, const float* __restrict__ cw,
    const float* __restrict__ cb, float* __restrict__ uc)
{
    int idx = blockIdx.x * 256 + threadIdx.x;   // b*2^21 + l*512 + d
    int d = idx & 511;
    int l = (idx >> 9) & 4095;
    int b = idx >> 21;
    float acc = cb[d];
#pragma unroll
    for (int k = 0; k < 4; ++k) {
        int ls = l + k - 3;
        if (ls >= 0)
            acc = fmaf(xz[((size_t)b * LL + ls) * 1024 + d], cw[d * 4 + k], acc);
    }
    uc[idx] = acc / (1.f + __expf(-acc));
}

// K6: selective scan. 16 lanes per (b,d) chain (lane = state n), 16 chains/block.
// Chunks of 64 steps staged through LDS. Writes gated y into xz cols 0..511.
__global__ __launch_bounds__(256) void scan_kernel(
    const float* __restrict__ delta, const float* __restrict__ uc,
    const float* __restrict__ xz, const float* __restrict__ dbl,
    const float* __restrict__ A_log, const float* __restrict__ Dsk,
    float* __restrict__ yout)
{
    const int b = blockIdx.x >> 5;
    const int d0 = (blockIdx.x & 31) << 4;
    const int tid = threadIdx.x;
    const int grp = tid >> 4;
    const int n = tid & 15;
    const int d = d0 + grp;
    const float An = -__expf(A_log[d * NS + n]);
    const float Dd = Dsk[d];
    __shared__ float sd[64][16], su[64][16], sz[64][16], sB[64][16], sC[64][16], sy[64][16];
    const int lrow = tid >> 2;
    const int lj = (tid & 3) << 2;
    float h = 0.f;
    const size_t base = (size_t)b * LL;
    for (int l0 = 0; l0 < LL; l0 += 64) {
        __syncthreads();
        size_t r = base + l0 + lrow;
        *(float4*)&sd[lrow][lj] = *(const float4*)&delta[r * 512 + d0 + lj];
        *(float4*)&su[lrow][lj] = *(const float4*)&uc[r * 512 + d0 + lj];
        *(float4*)&sz[lrow][lj] = *(const float4*)&xz[r * 1024 + 512 + d0 + lj];
        *(float4*)&sB[lrow][lj] = *(const float4*)&dbl[r * 48 + 16 + lj];
        *(float4*)&sC[lrow][lj] = *(const float4*)&dbl[r * 48 + 32 + lj];
        __syncthreads();
#pragma unroll 8
        for (int s = 0; s < 64; ++s) {
            float dv = sd[s][grp], uv = su[s][grp];
            float Bv = sB[s][n], Cv = sC[s][n];
            float dA = __expf(dv * An);
            h = fmaf(dA, h, dv * uv * Bv);
            float p = h * Cv;
            p += __shfl_xor(p, 1, 64);
            p += __shfl_xor(p, 2, 64);
            p += __shfl_xor(p, 4, 64);
            p += __shfl_xor(p, 8, 64);
            if (n == 0) {
                float zv = sz[s][grp];
                float sig = 1.f / (1.f + __expf(-zv));
                sy[s][grp] = (p + uv * Dd) * (zv * sig);
            }
        }
        __syncthreads();
        *(float4*)&yout[(base + l0 + lrow) * 1024 + d0 + lj] = *(float4*)&sy[lrow][lj];
    }
}

// K8a: SE spatial mean (partial sums + atomics into s[b,c])
__global__ __launch_bounds__(256) void se_mean(
    const float* __restrict__ mout, float* __restrict__ s)
{
    int b = blockIdx.x >> 5;
    int ch = blockIdx.x & 31;
    int c = threadIdx.x;
    float acc = 0.f;
    for (int l = ch * 128; l < ch * 128 + 128; ++l)
        acc += mout[((size_t)b * LL + l) * CC + c];
    atomicAdd(&s[b * CC + c], acc);
}

// K8b: SE gate: g = sigmoid(W2 @ relu(W1 @ mean))
__global__ __launch_bounds__(256) void se_gate(
    const float* __restrict__ s, const float* __restrict__ w1,
    const float* __restrict__ w2, float* __restrict__ g)
{
    __shared__ float sv[256];
    __shared__ float rr[16];
    int b = blockIdx.x;
    int c = threadIdx.x;
    sv[c] = s[b * CC + c] * (1.f / 4096.f);
    __syncthreads();
    if (c < 16) {
        float a = 0.f;
        for (int k = 0; k < 256; ++k) a = fmaf(sv[k], w1[c * 256 + k], a);
        rr[c] = fmaxf(a, 0.f);
    }
    __syncthreads();
    float a2 = 0.f;
#pragma unroll
    for (int j = 0; j < 16; ++j) a2 = fmaf(rr[j], w2[c * 16 + j], a2);
    g[b * CC + c] = 1.f / (1.f + __expf(-a2));
}

// K9: out[b,c,l] = x[b,c,l] + mout[b,l,c] * g[b,c]  (tiled transpose)
__global__ void final_kernel(
    const float* __restrict__ x, const float* __restrict__ mout,
    const float* __restrict__ g, float* __restrict__ out)
{
    __shared__ float t[32][33];
    int b = blockIdx.z;
    int c0 = blockIdx.y * 32;
    int l0 = blockIdx.x * 32;
    int lx = threadIdx.x;   // 0..31
    int ly = threadIdx.y;   // 0..7
#pragma unroll
    for (int i = 0; i < 4; ++i) {
        int ll = ly + 8 * i;
        t[ll][lx] = mout[((size_t)b * LL + l0 + ll) * CC + c0 + lx];
    }
    __syncthreads();
#pragma unroll
    for (int i = 0; i < 4; ++i) {
        int cc = ly + 8 * i;
        float gv = g[b * CC + c0 + cc];
        size_t o = ((size_t)b * CC + c0 + cc) * LL + l0 + lx;
        out[o] = x[o] + t[lx][cc] * gv;
    }
}

extern "C" void kernel_launch(void* const* d_in, const int* in_sizes, int n_in,
                              void* d_out, int out_size, void* d_ws, size_t ws_size,
                              hipStream_t stream)
{
    const float* x         = (const float*)d_in[0];
    const float* ln_vil_w  = (const float*)d_in[1];
    const float* mn_w      = (const float*)d_in[2];
    const float* mn_b      = (const float*)d_in[3];
    const float* in_proj_w = (const float*)d_in[4];
    const float* conv_w    = (const float*)d_in[5];
    const float* conv_b    = (const float*)d_in[6];
    const float* x_proj_w  = (const float*)d_in[7];
    const float* dt_proj_w = (const float*)d_in[8];
    const float* dt_proj_b = (const float*)d_in[9];
    const float* A_log     = (const float*)d_in[10];
    const float* Dsk       = (const float*)d_in[11];
    const float* out_proj_w= (const float*)d_in[12];
    const float* se_w1     = (const float*)d_in[13];
    const float* se_w2     = (const float*)d_in[14];
    float* out = (float*)d_out;

    char* ws = (char*)d_ws;
    float* hn    = (float*)(ws + HN_OFF);    // [16384,256]; later reused as mout
    float* xz    = (float*)(ws + XZ_OFF);    // [16384,1024]
    float* uc    = (float*)(ws + UC_OFF);    // [16384,512]
    float* dbl   = (float*)(ws + DBL_OFF);   // [16384,48]
    float* delta = (float*)(ws + DEL_OFF);   // [16384,512]
    float* sbufp = (float*)(ws + S_OFF);     // [4,256]
    float* gbufp = (float*)(ws + G_OFF);     // [4,256]
    float* mout  = hn;                       // alias: hn dead after in_proj

    // 1. transpose + double LN
    ln2_kernel<<<BB * LL, 256, 0, stream>>>(x, ln_vil_w, mn_w, mn_b, hn);
    // 2. in_proj: [16384,256] x [1024,256]^T -> xz [16384,1024]
    gemm_tn<0><<<dim3(256, 16), 256, 0, stream>>>(hn, 256, in_proj_w, 256, xz, 1024, 1024, 256, nullptr);
    // 3. depthwise causal conv + SiLU -> uc
    conv_silu<<<(BB * LL * DI) / 256, 256, 0, stream>>>(xz, conv_w, conv_b, uc);
    // 4. x_proj: [16384,512] x [48,512]^T -> dbl [16384,48]
    gemm_tn<0><<<dim3(256, 1), 256, 0, stream>>>(uc, 512, x_proj_w, 512, dbl, 48, 48, 512, nullptr);
    // 5. dt_proj + softplus: [16384,16] x [512,16]^T -> delta [16384,512]
    gemm_tn<1><<<dim3(256, 8), 256, 0, stream>>>(dbl, 48, dt_proj_w, 16, delta, 512, 512, 16, dt_proj_b);
    // 6. selective scan (writes gated y into xz cols 0..511)
    scan_kernel<<<128, 256, 0, stream>>>(delta, uc, xz, dbl, A_log, Dsk, xz);
    // 7. out_proj: y [16384,512] (lda=1024) x [256,512]^T -> mout [16384,256]
    gemm_tn<0><<<dim3(256, 4), 256, 0, stream>>>(xz, 1024, out_proj_w, 512, mout, 256, 256, 512, nullptr);
    // 8. SE attention
    hipMemsetAsync(sbufp, 0, BB * CC * sizeof(float), stream);
    se_mean<<<BB * 32, 256, 0, stream>>>(mout, sbufp);
    se_gate<<<BB, 256, 0, stream>>>(sbufp, se_w1, se_w2, gbufp);
    // 9. residual + gate + transpose back
    final_kernel<<<dim3(LL / 32, CC / 32, BB), dim3(32, 8), 0, stream>>>(x, mout, gbufp, out);
}

// Round 2
// 532.948 us; speedup vs baseline: 2.7014x; 2.7014x over previous
//
#include <hip/hip_runtime.h>
#include <hip/hip_bf16.h>
#include <math.h>

// Problem constants
#define BB 4
#define CC 256        // DIM
#define LL 4096       // H*W
#define DI 512        // D_INNER
#define NS 16         // D_STATE
#define RK 16         // DT_RANK

// Chunked scan config
#define GCH 64        // chunks
#define TCH 64        // steps per chunk (GCH*TCH == LL)

// Workspace layout (bytes). Total ~154 MB.
// [0,16MB): hn (ln output) -> dead after in_proj -> reused as scan scratch
//           Ap_buf [64][32768] @0, He_buf [64][32768] @8MB  -> dead after scan
//           -> reused again as mout [16384,256] for out_proj output
#define HN_OFF   0ull
#define AP_OFF   0ull
#define HE_OFF   8388608ull
#define XZ_OFF   16777216ull     // xz [16384,1024] ; cols 0..511 = u, later y ; cols 512..1023 = z
#define UC_OFF   83886080ull     // uc [16384,512]
#define DBL_OFF  117440512ull    // dbl [16384,48]  (dt | B | C)
#define DEL_OFF  120586240ull    // delta [16384,512]
#define S_OFF    154140672ull    // s [4,256]
#define G_OFF    154144768ull    // g [4,256]

__device__ __forceinline__ float block_sum_256(float v, float* sbuf) {
#pragma unroll
    for (int off = 32; off > 0; off >>= 1) v += __shfl_down(v, off, 64);
    int wid = threadIdx.x >> 6, lane = threadIdx.x & 63;
    __syncthreads();
    if (lane == 0) sbuf[wid] = v;
    __syncthreads();
    return sbuf[0] + sbuf[1] + sbuf[2] + sbuf[3];
}

// K1: transpose read + double LayerNorm. One block per token (256 threads = channels).
__global__ __launch_bounds__(256) void ln2_kernel(
    const float* __restrict__ x, const float* __restrict__ w1,
    const float* __restrict__ w2, const float* __restrict__ b2,
    float* __restrict__ hn)
{
    __shared__ float sbuf[4];
    int tok = blockIdx.x;            // b*4096 + l
    int b = tok >> 12;
    int l = tok & 4095;
    int c = threadIdx.x;
    float v = x[((size_t)b * CC + c) * LL + l];
    float mu = block_sum_256(v, sbuf) * (1.f / 256.f);
    float xc = v - mu;
    float var = block_sum_256(xc * xc, sbuf) * (1.f / 256.f);
    float y1 = xc * rsqrtf(var + 1e-5f) * w1[c];
    float mu2 = block_sum_256(y1, sbuf) * (1.f / 256.f);
    float y1c = y1 - mu2;
    float var2 = block_sum_256(y1c * y1c, sbuf) * (1.f / 256.f);
    float y2 = y1c * rsqrtf(var2 + 1e-5f) * w2[c] + b2[c];
    hn[(size_t)tok * CC + c] = y2;
}

// Generic fp32 GEMM: out[m,n] = sum_k A[m*lda+k] * Bw[n*ldb+k]   (both K-contiguous)
// EPI==1: out = softplus(acc + bias[n])
template<int EPI>
__global__ __launch_bounds__(256) void gemm_tn(
    const float* __restrict__ A, int lda,
    const float* __restrict__ Bw, int ldb,
    float* __restrict__ Co, int ldo,
    int N, int K, const float* __restrict__ bias)
{
    __shared__ float As[16][68];
    __shared__ float Bs[16][68];
    const int m0 = blockIdx.x * 64;
    const int n0 = blockIdx.y * 64;
    const int tid = threadIdx.x;
    const int row = tid >> 2;          // 0..63
    const int kj  = (tid & 3) << 2;    // 0,4,8,12
    const int tx = tid & 15, ty = tid >> 4;
    float acc[4][4] = {};
    for (int k0 = 0; k0 < K; k0 += 16) {
        float4 av = *reinterpret_cast<const float4*>(A + (size_t)(m0 + row) * lda + k0 + kj);
        As[kj + 0][row] = av.x; As[kj + 1][row] = av.y;
        As[kj + 2][row] = av.z; As[kj + 3][row] = av.w;
        float4 bv = make_float4(0.f, 0.f, 0.f, 0.f);
        if (n0 + row < N)
            bv = *reinterpret_cast<const float4*>(Bw + (size_t)(n0 + row) * ldb + k0 + kj);
        Bs[kj + 0][row] = bv.x; Bs[kj + 1][row] = bv.y;
        Bs[kj + 2][row] = bv.z; Bs[kj + 3][row] = bv.w;
        __syncthreads();
#pragma unroll
        for (int kk = 0; kk < 16; ++kk) {
            float a[4], b[4];
#pragma unroll
            for (int i = 0; i < 4; ++i) a[i] = As[kk][ty * 4 + i];
#pragma unroll
            for (int j = 0; j < 4; ++j) b[j] = Bs[kk][tx * 4 + j];
#pragma unroll
            for (int i = 0; i < 4; ++i)
#pragma unroll
                for (int j = 0; j < 4; ++j)
                    acc[i][j] = fmaf(a[i], b[j], acc[i][j]);
        }
        __syncthreads();
    }
#pragma unroll
    for (int i = 0; i < 4; ++i) {
        int m = m0 + ty * 4 + i;
#pragma unroll
        for (int j = 0; j < 4; ++j) {
            int n = n0 + tx * 4 + j;
            if (n < N) {
                float v = acc[i][j];
                if (EPI == 1) {
                    v += bias[n];
                    v = (v > 20.f) ? v : log1pf(__expf(v));
                }
                Co[(size_t)m * ldo + n] = v;
            }
        }
    }
}

// K3: depthwise causal conv (k=4) + bias + SiLU. u read from xz cols 0..511.
__global__ __launch_bounds__(256) void conv_silu(
    const float* __restrict__ xz, const float* __restrict__ cw,
    const float* __restrict__ cb, float* __restrict__ uc)
{
    int idx = blockIdx.x * 256 + threadIdx.x;   // b*2^21 + l*512 + d
    int d = idx & 511;
    int l = (idx >> 9) & 4095;
    int b = idx >> 21;
    float acc = cb[d];
#pragma unroll
    for (int k = 0; k < 4; ++k) {
        int ls = l + k - 3;
        if (ls >= 0)
            acc = fmaf(xz[((size_t)b * LL + ls) * 1024 + d], cw[d * 4 + k], acc);
    }
    uc[idx] = acc / (1.f + __expf(-acc));
}

// ---------------- Chunked selective scan (3 passes) ----------------
// Recurrence per (b,d,n): h_t = a_t h_{t-1} + b_t, a_t = exp(delta*A),
// b_t = delta*u*B. Linear -> blocked scan. One d per lane; 16 states in regs.

// S1: per-chunk local scan. Outputs cumulative decay Ap and local end state He.
// Layout: buf[((g*16+n)*4+b)*512 + d]  (coalesced in d).
__global__ __launch_bounds__(256) void scan_part1(
    const float* __restrict__ delta, const float* __restrict__ uc,
    const float* __restrict__ dbl, const float* __restrict__ A_log,
    float* __restrict__ Ap_buf, float* __restrict__ He_buf)
{
    const int d = blockIdx.x * 256 + threadIdx.x;   // 0..511
    const int g = blockIdx.y;                        // chunk
    const int b = blockIdx.z;
    float An[16], h[16], Ap[16];
#pragma unroll
    for (int n = 0; n < 16; ++n) {
        An[n] = -__expf(A_log[d * 16 + n]);
        h[n] = 0.f; Ap[n] = 1.f;
    }
    const size_t r0 = (size_t)b * LL + g * TCH;
    float dv = delta[r0 * 512 + d];
    float uv = uc[r0 * 512 + d];
    for (int s = 0; s < TCH; ++s) {
        const size_t rr = r0 + s;
        float Bv[16];
#pragma unroll
        for (int n = 0; n < 16; ++n) Bv[n] = dbl[rr * 48 + 16 + n];
        float dvc = dv, uvc = uv;
        if (s < TCH - 1) {
            dv = delta[(rr + 1) * 512 + d];
            uv = uc[(rr + 1) * 512 + d];
        }
        float duv = dvc * uvc;
#pragma unroll
        for (int n = 0; n < 16; ++n) {
            float e = __expf(dvc * An[n]);
            Ap[n] *= e;
            h[n] = fmaf(e, h[n], duv * Bv[n]);
        }
    }
#pragma unroll
    for (int n = 0; n < 16; ++n) {
        size_t o = (size_t)((g * 16 + n) * 4 + b) * 512 + d;
        Ap_buf[o] = Ap[n];
        He_buf[o] = h[n];
    }
}

// S2: cross-chunk prefix. One thread per (b,d,n) chain. In-place: He becomes h_in.
__global__ __launch_bounds__(256) void scan_part2(
    const float* __restrict__ Ap_buf, float* __restrict__ He_buf)
{
    const int c = blockIdx.x * 256 + threadIdx.x;   // (n*4+b)*512+d
    float h = 0.f;
    for (int g = 0; g < GCH; ++g) {
        size_t o = (size_t)g * 32768 + c;
        float a = Ap_buf[o];
        float e = He_buf[o];
        He_buf[o] = h;                 // h_in for this chunk
        h = fmaf(a, h, e);
    }
}

// S3: replay each chunk from h_in, produce gated y into xz cols 0..511.
__global__ __launch_bounds__(256) void scan_part3(
    const float* __restrict__ delta, const float* __restrict__ uc,
    const float* __restrict__ xz, const float* __restrict__ dbl,
    const float* __restrict__ A_log, const float* __restrict__ Dsk,
    const float* __restrict__ Hin, float* __restrict__ yout)
{
    const int d = blockIdx.x * 256 + threadIdx.x;
    const int g = blockIdx.y;
    const int b = blockIdx.z;
    float An[16], h[16];
#pragma unroll
    for (int n = 0; n < 16; ++n) {
        An[n] = -__expf(A_log[d * 16 + n]);
        h[n] = Hin[(size_t)((g * 16 + n) * 4 + b) * 512 + d];
    }
    const float Dd = Dsk[d];
    const size_t r0 = (size_t)b * LL + g * TCH;
    float dv = delta[r0 * 512 + d];
    float uv = uc[r0 * 512 + d];
    float zv = xz[r0 * 1024 + 512 + d];
    for (int s = 0; s < TCH; ++s) {
        const size_t rr = r0 + s;
        float Bv[16], Cv[16];
#pragma unroll
        for (int n = 0; n < 16; ++n) {
            Bv[n] = dbl[rr * 48 + 16 + n];
            Cv[n] = dbl[rr * 48 + 32 + n];
        }
        float dvc = dv, uvc = uv, zvc = zv;
        if (s < TCH - 1) {
            dv = delta[(rr + 1) * 512 + d];
            uv = uc[(rr + 1) * 512 + d];
            zv = xz[(rr + 1) * 1024 + 512 + d];
        }
        float duv = dvc * uvc;
        float y = 0.f;
#pragma unroll
        for (int n = 0; n < 16; ++n) {
            float e = __expf(dvc * An[n]);
            h[n] = fmaf(e, h[n], duv * Bv[n]);
            y = fmaf(h[n], Cv[n], y);
        }
        y = fmaf(uvc, Dd, y);
        float sig = 1.f / (1.f + __expf(-zvc));
        yout[rr * 1024 + d] = y * (zvc * sig);
    }
}

// K8a: SE spatial mean (partial sums + atomics into s[b,c])
__global__ __launch_bounds__(256) void se_mean(
    const float* __restrict__ mout, float* __restrict__ s)
{
    int b = blockIdx.x >> 5;
    int ch = blockIdx.x & 31;
    int c = threadIdx.x;
    float acc = 0.f;
    for (int l = ch * 128; l < ch * 128 + 128; ++l)
        acc += mout[((size_t)b * LL + l) * CC + c];
    atomicAdd(&s[b * CC + c], acc);
}

// K8b: SE gate: g = sigmoid(W2 @ relu(W1 @ mean))
__global__ __launch_bounds__(256) void se_gate(
    const float* __restrict__ s, const float* __restrict__ w1,
    const float* __restrict__ w2, float* __restrict__ g)
{
    __shared__ float sv[256];
    __shared__ float rr[16];
    int b = blockIdx.x;
    int c = threadIdx.x;
    sv[c] = s[b * CC + c] * (1.f / 4096.f);
    __syncthreads();
    if (c < 16) {
        float a = 0.f;
        for (int k = 0; k < 256; ++k) a = fmaf(sv[k], w1[c * 256 + k], a);
        rr[c] = fmaxf(a, 0.f);
    }
    __syncthreads();
    float a2 = 0.f;
#pragma unroll
    for (int j = 0; j < 16; ++j) a2 = fmaf(rr[j], w2[c * 16 + j], a2);
    g[b * CC + c] = 1.f / (1.f + __expf(-a2));
}

// K9: out[b,c,l] = x[b,c,l] + mout[b,l,c] * g[b,c]  (tiled transpose)
__global__ void final_kernel(
    const float* __restrict__ x, const float* __restrict__ mout,
    const float* __restrict__ g, float* __restrict__ out)
{
    __shared__ float t[32][33];
    int b = blockIdx.z;
    int c0 = blockIdx.y * 32;
    int l0 = blockIdx.x * 32;
    int lx = threadIdx.x;   // 0..31
    int ly = threadIdx.y;   // 0..7
#pragma unroll
    for (int i = 0; i < 4; ++i) {
        int ll = ly + 8 * i;
        t[ll][lx] = mout[((size_t)b * LL + l0 + ll) * CC + c0 + lx];
    }
    __syncthreads();
#pragma unroll
    for (int i = 0; i < 4; ++i) {
        int cc = ly + 8 * i;
        float gv = g[b * CC + c0 + cc];
        size_t o = ((size_t)b * CC + c0 + cc) * LL + l0 + lx;
        out[o] = x[o] + t[lx][cc] * gv;
    }
}

extern "C" void kernel_launch(void* const* d_in, const int* in_sizes, int n_in,
                              void* d_out, int out_size, void* d_ws, size_t ws_size,
                              hipStream_t stream)
{
    const float* x         = (const float*)d_in[0];
    const float* ln_vil_w  = (const float*)d_in[1];
    const float* mn_w      = (const float*)d_in[2];
    const float* mn_b      = (const float*)d_in[3];
    const float* in_proj_w = (const float*)d_in[4];
    const float* conv_w    = (const float*)d_in[5];
    const float* conv_b    = (const float*)d_in[6];
    const float* x_proj_w  = (const float*)d_in[7];
    const float* dt_proj_w = (const float*)d_in[8];
    const float* dt_proj_b = (const float*)d_in[9];
    const float* A_log     = (const float*)d_in[10];
    const float* Dsk       = (const float*)d_in[11];
    const float* out_proj_w= (const float*)d_in[12];
    const float* se_w1     = (const float*)d_in[13];
    const float* se_w2     = (const float*)d_in[14];
    float* out = (float*)d_out;

    char* ws = (char*)d_ws;
    float* hn    = (float*)(ws + HN_OFF);    // [16384,256]; reused as scan scratch then mout
    float* apb   = (float*)(ws + AP_OFF);    // [64][32768]
    float* heb   = (float*)(ws + HE_OFF);    // [64][32768]
    float* xz    = (float*)(ws + XZ_OFF);    // [16384,1024]
    float* uc    = (float*)(ws + UC_OFF);    // [16384,512]
    float* dbl   = (float*)(ws + DBL_OFF);   // [16384,48]
    float* delta = (float*)(ws + DEL_OFF);   // [16384,512]
    float* sbufp = (float*)(ws + S_OFF);     // [4,256]
    float* gbufp = (float*)(ws + G_OFF);     // [4,256]
    float* mout  = hn;                       // alias: hn/scan-scratch dead by out_proj

    // 1. transpose + double LN
    ln2_kernel<<<BB * LL, 256, 0, stream>>>(x, ln_vil_w, mn_w, mn_b, hn);
    // 2. in_proj: [16384,256] x [1024,256]^T -> xz [16384,1024]
    gemm_tn<0><<<dim3(256, 16), 256, 0, stream>>>(hn, 256, in_proj_w, 256, xz, 1024, 1024, 256, nullptr);
    // 3. depthwise causal conv + SiLU -> uc
    conv_silu<<<(BB * LL * DI) / 256, 256, 0, stream>>>(xz, conv_w, conv_b, uc);
    // 4. x_proj: [16384,512] x [48,512]^T -> dbl [16384,48]
    gemm_tn<0><<<dim3(256, 1), 256, 0, stream>>>(uc, 512, x_proj_w, 512, dbl, 48, 48, 512, nullptr);
    // 5. dt_proj + softplus: [16384,16] x [512,16]^T -> delta [16384,512]
    gemm_tn<1><<<dim3(256, 8), 256, 0, stream>>>(dbl, 48, dt_proj_w, 16, delta, 512, 512, 16, dt_proj_b);
    // 6. chunked selective scan (writes gated y into xz cols 0..511)
    scan_part1<<<dim3(2, GCH, BB), 256, 0, stream>>>(delta, uc, dbl, A_log, apb, heb);
    scan_part2<<<128, 256, 0, stream>>>(apb, heb);
    scan_part3<<<dim3(2, GCH, BB), 256, 0, stream>>>(delta, uc, xz, dbl, A_log, Dsk, heb, xz);
    // 7. out_proj: y [16384,512] (lda=1024) x [256,512]^T -> mout [16384,256]
    gemm_tn<0><<<dim3(256, 4), 256, 0, stream>>>(xz, 1024, out_proj_w, 512, mout, 256, 256, 512, nullptr);
    // 8. SE attention
    hipMemsetAsync(sbufp, 0, BB * CC * sizeof(float), stream);
    se_mean<<<BB * 32, 256, 0, stream>>>(mout, sbufp);
    se_gate<<<BB, 256, 0, stream>>>(sbufp, se_w1, se_w2, gbufp);
    // 9. residual + gate + transpose back
    final_kernel<<<dim3(LL / 32, CC / 32, BB), dim3(32, 8), 0, stream>>>(x, mout, gbufp, out);
}

// Round 3
// 404.154 us; speedup vs baseline: 3.5623x; 1.3187x over previous
//
#include <hip/hip_runtime.h>
#include <hip/hip_bf16.h>
#include <math.h>

// Problem constants
#define BB 4
#define CC 256        // DIM
#define LL 4096       // H*W
#define DI 512        // D_INNER
#define NS 16         // D_STATE
#define RK 16         // DT_RANK

// Chunked scan config
#define GCH 64        // chunks
#define TCH 64        // steps per chunk (GCH*TCH == LL)

// Workspace layout (bytes). Total ~154 MB.
#define HN_OFF   0ull
#define AP_OFF   0ull
#define HE_OFF   8388608ull
#define XZ_OFF   16777216ull     // xz [16384,1024] ; cols 0..511 = u, later y ; cols 512..1023 = z
#define UC_OFF   83886080ull     // uc [16384,512]
#define DBL_OFF  117440512ull    // dbl [16384,48]  (dt | B | C)
#define DEL_OFF  120586240ull    // delta [16384,512]
#define S_OFF    154140672ull    // s [4,256]
#define G_OFF    154144768ull    // g [4,256]

typedef __attribute__((ext_vector_type(8))) short bf16x8;
typedef __attribute__((ext_vector_type(4))) short bf16x4;
typedef __attribute__((ext_vector_type(4))) float f32x4;

__device__ __forceinline__ short f2bf(float f) {
    unsigned u = __float_as_uint(f);
    u += 0x7fff + ((u >> 16) & 1);
    return (short)(u >> 16);
}

__device__ __forceinline__ float block_sum_256(float v, float* sbuf) {
#pragma unroll
    for (int off = 32; off > 0; off >>= 1) v += __shfl_down(v, off, 64);
    int wid = threadIdx.x >> 6, lane = threadIdx.x & 63;
    __syncthreads();
    if (lane == 0) sbuf[wid] = v;
    __syncthreads();
    return sbuf[0] + sbuf[1] + sbuf[2] + sbuf[3];
}

// K1: transpose read + double LayerNorm. One block per token (256 threads = channels).
__global__ __launch_bounds__(256) void ln2_kernel(
    const float* __restrict__ x, const float* __restrict__ w1,
    const float* __restrict__ w2, const float* __restrict__ b2,
    float* __restrict__ hn)
{
    __shared__ float sbuf[4];
    int tok = blockIdx.x;            // b*4096 + l
    int b = tok >> 12;
    int l = tok & 4095;
    int c = threadIdx.x;
    float v = x[((size_t)b * CC + c) * LL + l];
    float mu = block_sum_256(v, sbuf) * (1.f / 256.f);
    float xc = v - mu;
    float var = block_sum_256(xc * xc, sbuf) * (1.f / 256.f);
    float y1 = xc * rsqrtf(var + 1e-5f) * w1[c];
    float mu2 = block_sum_256(y1, sbuf) * (1.f / 256.f);
    float y1c = y1 - mu2;
    float var2 = block_sum_256(y1c * y1c, sbuf) * (1.f / 256.f);
    float y2 = y1c * rsqrtf(var2 + 1e-5f) * w2[c] + b2[c];
    hn[(size_t)tok * CC + c] = y2;
}

// ---------------- MFMA bf16 GEMM (gemm_bt): out[m,n] = sum_k A[m,k]*Bw[n,k] ----------------
// A, Bw are fp32 in global; converted to bf16 during LDS staging. fp32 accumulate.
// Block tile 128 x BN, K-tile 32. 256 threads = 4 waves in 2x2 grid.
template<int BN>   // 128 or 64
__global__ __launch_bounds__(256) void gemm_bt_mfma(
    const float* __restrict__ A, int lda,
    const float* __restrict__ Bw, int ldb,
    float* __restrict__ Co, int ldo, int K)
{
    constexpr int NF = BN / 32;              // n-frags per wave
    __shared__ short As[128 * 40];           // row stride 40 bf16 = 80 B (16B aligned)
    __shared__ short Bs[BN * 40];
    const int m0 = blockIdx.x * 128;
    const int n0 = blockIdx.y * BN;
    const int tid = threadIdx.x;
    const int wave = tid >> 6;
    const int lane = tid & 63;
    const int wm = (wave >> 1) * 64;
    const int wn = (wave & 1) * (BN / 2);
    const int l15 = lane & 15;
    const int quad = lane >> 4;

    f32x4 acc[4][NF];
#pragma unroll
    for (int mt = 0; mt < 4; ++mt)
#pragma unroll
        for (int nt = 0; nt < NF; ++nt)
            acc[mt][nt] = (f32x4)(0.0f);

    for (int k0 = 0; k0 < K; k0 += 32) {
        __syncthreads();
        // stage A tile [128][32]
#pragma unroll
        for (int i = 0; i < 4; ++i) {
            int c = tid + 256 * i;           // 0..1023 chunks of 4 floats
            int row = c >> 3;
            int col = (c & 7) << 2;
            float4 v = *reinterpret_cast<const float4*>(A + (size_t)(m0 + row) * lda + k0 + col);
            bf16x4 bv = { f2bf(v.x), f2bf(v.y), f2bf(v.z), f2bf(v.w) };
            *reinterpret_cast<bf16x4*>(&As[row * 40 + col]) = bv;
        }
        // stage B tile [BN][32]
#pragma unroll
        for (int i = 0; i < BN / 32; ++i) {
            int c = tid + 256 * i;
            int row = c >> 3;
            int col = (c & 7) << 2;
            float4 v = *reinterpret_cast<const float4*>(Bw + (size_t)(n0 + row) * ldb + k0 + col);
            bf16x4 bv = { f2bf(v.x), f2bf(v.y), f2bf(v.z), f2bf(v.w) };
            *reinterpret_cast<bf16x4*>(&Bs[row * 40 + col]) = bv;
        }
        __syncthreads();

        bf16x8 af[4], bfr[NF];
#pragma unroll
        for (int mt = 0; mt < 4; ++mt)
            af[mt] = *reinterpret_cast<const bf16x8*>(&As[(wm + mt * 16 + l15) * 40 + quad * 8]);
#pragma unroll
        for (int nt = 0; nt < NF; ++nt)
            bfr[nt] = *reinterpret_cast<const bf16x8*>(&Bs[(wn + nt * 16 + l15) * 40 + quad * 8]);
#pragma unroll
        for (int mt = 0; mt < 4; ++mt)
#pragma unroll
            for (int nt = 0; nt < NF; ++nt)
                acc[mt][nt] = __builtin_amdgcn_mfma_f32_16x16x32_bf16(af[mt], bfr[nt], acc[mt][nt], 0, 0, 0);
    }
    // epilogue: C/D layout col=lane&15, row=quad*4+reg
#pragma unroll
    for (int mt = 0; mt < 4; ++mt)
#pragma unroll
        for (int nt = 0; nt < NF; ++nt) {
            int n = n0 + wn + nt * 16 + l15;
#pragma unroll
            for (int r = 0; r < 4; ++r) {
                int m = m0 + wm + mt * 16 + quad * 4 + r;
                Co[(size_t)m * ldo + n] = acc[mt][nt][r];
            }
        }
}

// Generic fp32 GEMM (kept for small x_proj / dt_proj): out[m,n] = sum_k A[m,k]*Bw[n,k]
// EPI==1: out = softplus(acc + bias[n])
template<int EPI>
__global__ __launch_bounds__(256) void gemm_tn(
    const float* __restrict__ A, int lda,
    const float* __restrict__ Bw, int ldb,
    float* __restrict__ Co, int ldo,
    int N, int K, const float* __restrict__ bias)
{
    __shared__ float As[16][68];
    __shared__ float Bs[16][68];
    const int m0 = blockIdx.x * 64;
    const int n0 = blockIdx.y * 64;
    const int tid = threadIdx.x;
    const int row = tid >> 2;          // 0..63
    const int kj  = (tid & 3) << 2;    // 0,4,8,12
    const int tx = tid & 15, ty = tid >> 4;
    float acc[4][4] = {};
    for (int k0 = 0; k0 < K; k0 += 16) {
        float4 av = *reinterpret_cast<const float4*>(A + (size_t)(m0 + row) * lda + k0 + kj);
        As[kj + 0][row] = av.x; As[kj + 1][row] = av.y;
        As[kj + 2][row] = av.z; As[kj + 3][row] = av.w;
        float4 bv = make_float4(0.f, 0.f, 0.f, 0.f);
        if (n0 + row < N)
            bv = *reinterpret_cast<const float4*>(Bw + (size_t)(n0 + row) * ldb + k0 + kj);
        Bs[kj + 0][row] = bv.x; Bs[kj + 1][row] = bv.y;
        Bs[kj + 2][row] = bv.z; Bs[kj + 3][row] = bv.w;
        __syncthreads();
#pragma unroll
        for (int kk = 0; kk < 16; ++kk) {
            float a[4], b[4];
#pragma unroll
            for (int i = 0; i < 4; ++i) a[i] = As[kk][ty * 4 + i];
#pragma unroll
            for (int j = 0; j < 4; ++j) b[j] = Bs[kk][tx * 4 + j];
#pragma unroll
            for (int i = 0; i < 4; ++i)
#pragma unroll
                for (int j = 0; j < 4; ++j)
                    acc[i][j] = fmaf(a[i], b[j], acc[i][j]);
        }
        __syncthreads();
    }
#pragma unroll
    for (int i = 0; i < 4; ++i) {
        int m = m0 + ty * 4 + i;
#pragma unroll
        for (int j = 0; j < 4; ++j) {
            int n = n0 + tx * 4 + j;
            if (n < N) {
                float v = acc[i][j];
                if (EPI == 1) {
                    v += bias[n];
                    v = (v > 20.f) ? v : log1pf(__expf(v));
                }
                Co[(size_t)m * ldo + n] = v;
            }
        }
    }
}

// K3: depthwise causal conv (k=4) + bias + SiLU. u read from xz cols 0..511.
__global__ __launch_bounds__(256) void conv_silu(
    const float* __restrict__ xz, const float* __restrict__ cw,
    const float* __restrict__ cb, float* __restrict__ uc)
{
    int idx = blockIdx.x * 256 + threadIdx.x;   // b*2^21 + l*512 + d
    int d = idx & 511;
    int l = (idx >> 9) & 4095;
    int b = idx >> 21;
    float acc = cb[d];
#pragma unroll
    for (int k = 0; k < 4; ++k) {
        int ls = l + k - 3;
        if (ls >= 0)
            acc = fmaf(xz[((size_t)b * LL + ls) * 1024 + d], cw[d * 4 + k], acc);
    }
    uc[idx] = acc / (1.f + __expf(-acc));
}

// ---------------- Chunked selective scan (3 passes) ----------------
__global__ __launch_bounds__(256) void scan_part1(
    const float* __restrict__ delta, const float* __restrict__ uc,
    const float* __restrict__ dbl, const float* __restrict__ A_log,
    float* __restrict__ Ap_buf, float* __restrict__ He_buf)
{
    const int d = blockIdx.x * 256 + threadIdx.x;   // 0..511
    const int g = blockIdx.y;                        // chunk
    const int b = blockIdx.z;
    float An[16], h[16], Ap[16];
#pragma unroll
    for (int n = 0; n < 16; ++n) {
        An[n] = -__expf(A_log[d * 16 + n]);
        h[n] = 0.f; Ap[n] = 1.f;
    }
    const size_t r0 = (size_t)b * LL + g * TCH;
    float dv = delta[r0 * 512 + d];
    float uv = uc[r0 * 512 + d];
    for (int s = 0; s < TCH; ++s) {
        const size_t rr = r0 + s;
        float Bv[16];
#pragma unroll
        for (int n = 0; n < 16; ++n) Bv[n] = dbl[rr * 48 + 16 + n];
        float dvc = dv, uvc = uv;
        if (s < TCH - 1) {
            dv = delta[(rr + 1) * 512 + d];
            uv = uc[(rr + 1) * 512 + d];
        }
        float duv = dvc * uvc;
#pragma unroll
        for (int n = 0; n < 16; ++n) {
            float e = __expf(dvc * An[n]);
            Ap[n] *= e;
            h[n] = fmaf(e, h[n], duv * Bv[n]);
        }
    }
#pragma unroll
    for (int n = 0; n < 16; ++n) {
        size_t o = (size_t)((g * 16 + n) * 4 + b) * 512 + d;
        Ap_buf[o] = Ap[n];
        He_buf[o] = h[n];
    }
}

__global__ __launch_bounds__(256) void scan_part2(
    const float* __restrict__ Ap_buf, float* __restrict__ He_buf)
{
    const int c = blockIdx.x * 256 + threadIdx.x;   // (n*4+b)*512+d
    float h = 0.f;
    for (int g = 0; g < GCH; ++g) {
        size_t o = (size_t)g * 32768 + c;
        float a = Ap_buf[o];
        float e = He_buf[o];
        He_buf[o] = h;                 // h_in for this chunk
        h = fmaf(a, h, e);
    }
}

__global__ __launch_bounds__(256) void scan_part3(
    const float* __restrict__ delta, const float* __restrict__ uc,
    const float* __restrict__ xz, const float* __restrict__ dbl,
    const float* __restrict__ A_log, const float* __restrict__ Dsk,
    const float* __restrict__ Hin, float* __restrict__ yout)
{
    const int d = blockIdx.x * 256 + threadIdx.x;
    const int g = blockIdx.y;
    const int b = blockIdx.z;
    float An[16], h[16];
#pragma unroll
    for (int n = 0; n < 16; ++n) {
        An[n] = -__expf(A_log[d * 16 + n]);
        h[n] = Hin[(size_t)((g * 16 + n) * 4 + b) * 512 + d];
    }
    const float Dd = Dsk[d];
    const size_t r0 = (size_t)b * LL + g * TCH;
    float dv = delta[r0 * 512 + d];
    float uv = uc[r0 * 512 + d];
    float zv = xz[r0 * 1024 + 512 + d];
    for (int s = 0; s < TCH; ++s) {
        const size_t rr = r0 + s;
        float Bv[16], Cv[16];
#pragma unroll
        for (int n = 0; n < 16; ++n) {
            Bv[n] = dbl[rr * 48 + 16 + n];
            Cv[n] = dbl[rr * 48 + 32 + n];
        }
        float dvc = dv, uvc = uv, zvc = zv;
        if (s < TCH - 1) {
            dv = delta[(rr + 1) * 512 + d];
            uv = uc[(rr + 1) * 512 + d];
            zv = xz[(rr + 1) * 1024 + 512 + d];
        }
        float duv = dvc * uvc;
        float y = 0.f;
#pragma unroll
        for (int n = 0; n < 16; ++n) {
            float e = __expf(dvc * An[n]);
            h[n] = fmaf(e, h[n], duv * Bv[n]);
            y = fmaf(h[n], Cv[n], y);
        }
        y = fmaf(uvc, Dd, y);
        float sig = 1.f / (1.f + __expf(-zvc));
        yout[rr * 1024 + d] = y * (zvc * sig);
    }
}

// K8a: SE spatial mean (partial sums + atomics into s[b,c])
__global__ __launch_bounds__(256) void se_mean(
    const float* __restrict__ mout, float* __restrict__ s)
{
    int b = blockIdx.x >> 5;
    int ch = blockIdx.x & 31;
    int c = threadIdx.x;
    float acc = 0.f;
    for (int l = ch * 128; l < ch * 128 + 128; ++l)
        acc += mout[((size_t)b * LL + l) * CC + c];
    atomicAdd(&s[b * CC + c], acc);
}

// K8b: SE gate: g = sigmoid(W2 @ relu(W1 @ mean))
__global__ __launch_bounds__(256) void se_gate(
    const float* __restrict__ s, const float* __restrict__ w1,
    const float* __restrict__ w2, float* __restrict__ g)
{
    __shared__ float sv[256];
    __shared__ float rr[16];
    int b = blockIdx.x;
    int c = threadIdx.x;
    sv[c] = s[b * CC + c] * (1.f / 4096.f);
    __syncthreads();
    if (c < 16) {
        float a = 0.f;
        for (int k = 0; k < 256; ++k) a = fmaf(sv[k], w1[c * 256 + k], a);
        rr[c] = fmaxf(a, 0.f);
    }
    __syncthreads();
    float a2 = 0.f;
#pragma unroll
    for (int j = 0; j < 16; ++j) a2 = fmaf(rr[j], w2[c * 16 + j], a2);
    g[b * CC + c] = 1.f / (1.f + __expf(-a2));
}

// K9: out[b,c,l] = x[b,c,l] + mout[b,l,c] * g[b,c]  (tiled transpose)
__global__ void final_kernel(
    const float* __restrict__ x, const float* __restrict__ mout,
    const float* __restrict__ g, float* __restrict__ out)
{
    __shared__ float t[32][33];
    int b = blockIdx.z;
    int c0 = blockIdx.y * 32;
    int l0 = blockIdx.x * 32;
    int lx = threadIdx.x;   // 0..31
    int ly = threadIdx.y;   // 0..7
#pragma unroll
    for (int i = 0; i < 4; ++i) {
        int ll = ly + 8 * i;
        t[ll][lx] = mout[((size_t)b * LL + l0 + ll) * CC + c0 + lx];
    }
    __syncthreads();
#pragma unroll
    for (int i = 0; i < 4; ++i) {
        int cc = ly + 8 * i;
        float gv = g[b * CC + c0 + cc];
        size_t o = ((size_t)b * CC + c0 + cc) * LL + l0 + lx;
        out[o] = x[o] + t[lx][cc] * gv;
    }
}

extern "C" void kernel_launch(void* const* d_in, const int* in_sizes, int n_in,
                              void* d_out, int out_size, void* d_ws, size_t ws_size,
                              hipStream_t stream)
{
    const float* x         = (const float*)d_in[0];
    const float* ln_vil_w  = (const float*)d_in[1];
    const float* mn_w      = (const float*)d_in[2];
    const float* mn_b      = (const float*)d_in[3];
    const float* in_proj_w = (const float*)d_in[4];
    const float* conv_w    = (const float*)d_in[5];
    const float* conv_b    = (const float*)d_in[6];
    const float* x_proj_w  = (const float*)d_in[7];
    const float* dt_proj_w = (const float*)d_in[8];
    const float* dt_proj_b = (const float*)d_in[9];
    const float* A_log     = (const float*)d_in[10];
    const float* Dsk       = (const float*)d_in[11];
    const float* out_proj_w= (const float*)d_in[12];
    const float* se_w1     = (const float*)d_in[13];
    const float* se_w2     = (const float*)d_in[14];
    float* out = (float*)d_out;

    char* ws = (char*)d_ws;
    float* hn    = (float*)(ws + HN_OFF);    // [16384,256]; reused as scan scratch then mout
    float* apb   = (float*)(ws + AP_OFF);    // [64][32768]
    float* heb   = (float*)(ws + HE_OFF);    // [64][32768]
    float* xz    = (float*)(ws + XZ_OFF);    // [16384,1024]
    float* uc    = (float*)(ws + UC_OFF);    // [16384,512]
    float* dbl   = (float*)(ws + DBL_OFF);   // [16384,48]
    float* delta = (float*)(ws + DEL_OFF);   // [16384,512]
    float* sbufp = (float*)(ws + S_OFF);     // [4,256]
    float* gbufp = (float*)(ws + G_OFF);     // [4,256]
    float* mout  = hn;                       // alias: hn/scan-scratch dead by out_proj

    // 1. transpose + double LN
    ln2_kernel<<<BB * LL, 256, 0, stream>>>(x, ln_vil_w, mn_w, mn_b, hn);
    // 2. in_proj (bf16 MFMA): [16384,256] x [1024,256]^T -> xz [16384,1024]
    gemm_bt_mfma<128><<<dim3(128, 8), 256, 0, stream>>>(hn, 256, in_proj_w, 256, xz, 1024, 256);
    // 3. depthwise causal conv + SiLU -> uc
    conv_silu<<<(BB * LL * DI) / 256, 256, 0, stream>>>(xz, conv_w, conv_b, uc);
    // 4. x_proj: [16384,512] x [48,512]^T -> dbl [16384,48]
    gemm_tn<0><<<dim3(256, 1), 256, 0, stream>>>(uc, 512, x_proj_w, 512, dbl, 48, 48, 512, nullptr);
    // 5. dt_proj + softplus: [16384,16] x [512,16]^T -> delta [16384,512]
    gemm_tn<1><<<dim3(256, 8), 256, 0, stream>>>(dbl, 48, dt_proj_w, 16, delta, 512, 512, 16, dt_proj_b);
    // 6. chunked selective scan (writes gated y into xz cols 0..511)
    scan_part1<<<dim3(2, GCH, BB), 256, 0, stream>>>(delta, uc, dbl, A_log, apb, heb);
    scan_part2<<<128, 256, 0, stream>>>(apb, heb);
    scan_part3<<<dim3(2, GCH, BB), 256, 0, stream>>>(delta, uc, xz, dbl, A_log, Dsk, heb, xz);
    // 7. out_proj (bf16 MFMA): y [16384,512] (lda=1024) x [256,512]^T -> mout [16384,256]
    gemm_bt_mfma<64><<<dim3(128, 4), 256, 0, stream>>>(xz, 1024, out_proj_w, 512, mout, 256, 512);
    // 8. SE attention
    hipMemsetAsync(sbufp, 0, BB * CC * sizeof(float), stream);
    se_mean<<<BB * 32, 256, 0, stream>>>(mout, sbufp);
    se_gate<<<BB, 256, 0, stream>>>(sbufp, se_w1, se_w2, gbufp);
    // 9. residual + gate + transpose back
    final_kernel<<<dim3(LL / 32, CC / 32, BB), dim3(32, 8), 0, stream>>>(x, mout, gbufp, out);
}